// Round 1
// baseline (251.639 us; speedup 1.0000x reference)
//
#include <hip/hip_runtime.h>
#include <hip/hip_bf16.h>

// PrototypeConsistentLearning: loss = mean(-pos + lse_neg), new_protos = serial EMA.
// B=8192, D=512, K=16384, T=0.5, momentum=0.9.
// R7: flash GEMM rebuilt on the 256^2 8-wave deep-pipeline template (guide §5
// T3+T4+T5): 4 phases per K-step (phase = one 64x32 C-quadrant x K=128, 8 MFMAs),
// raw s_barrier + s_setprio(1) around MFMA clusters, and COUNTED s_waitcnt
// vmcnt(4) at step boundaries -- A(s+2) is issued into the just-freed LDS buffer
// before the wait, so 4 global_load_lds (32KB/block) stay in flight across every
// barrier (the old structure drained vmcnt(0) every chunk -> 29% MfmaUtil).
// LDS 128KB: A[2][256x128] + B[2][256x128] fp8, double-buffered; 1 block/CU,
// 8 waves (2M x 4N), per-wave C = 128x64. Same x16 e4m3 quantization, same XOR
// granule swizzle (stored granule = logical ^ (row&7), inverse applied at the
// global source since gl_lds writes linearly). pos/EMA exact fp32, unchanged.

#define B_N 8192
#define D_N 512
#define K_N 16384
#define INV_T 2.0f
#define MOM 0.9f

#define BM 256
#define BN 256
#define BKF 128
#define CT 4            // column tiles per block
#define NT (CT * 4)     // total K-steps per block (CT tiles x D/BKF chunks)
#define CAP 64

typedef __attribute__((ext_vector_type(8))) int intx8;
typedef __attribute__((ext_vector_type(4))) float floatx4;

__device__ __forceinline__ void gl_lds16(const void* g, void* lds) {
    __builtin_amdgcn_global_load_lds(
        (const __attribute__((address_space(1))) void*)g,
        (__attribute__((address_space(3))) void*)lds, 16, 0, 0);
}

// ---- normalize rows (fp32) -> e4m3 fp8 scaled by 16; also zero rowsum/out[0]. ----
__global__ void norm_kernel(const float* __restrict__ emb, const float* __restrict__ pro,
                            unsigned char* __restrict__ embq, unsigned char* __restrict__ proq,
                            float* __restrict__ rowsum, float* __restrict__ out) {
    if (blockIdx.x < 32) rowsum[blockIdx.x * 256 + threadIdx.x] = 0.0f;
    if (blockIdx.x == 32 && threadIdx.x == 0) out[0] = 0.0f;
    int row = blockIdx.x * 4 + (threadIdx.x >> 6);
    int lane = threadIdx.x & 63;
    const float* x;
    unsigned char* o;
    if (row < B_N) {
        x = emb + (size_t)row * D_N;
        o = embq + (size_t)row * D_N;
    } else {
        x = pro + (size_t)(row - B_N) * D_N;
        o = proq + (size_t)(row - B_N) * D_N;
    }
    const float4* xp = (const float4*)(x + lane * 8);
    float4 v0 = xp[0];
    float4 v1 = xp[1];
    float ss = v0.x * v0.x + v0.y * v0.y + v0.z * v0.z + v0.w * v0.w +
               v1.x * v1.x + v1.y * v1.y + v1.z * v1.z + v1.w * v1.w;
    #pragma unroll
    for (int of = 32; of; of >>= 1) ss += __shfl_xor(ss, of);
    float sc = 16.0f / fmaxf(sqrtf(ss), 1e-12f);  // x16: e4m3 keeps full mantissa range
    int w0 = 0, w1 = 0;
    w0 = __builtin_amdgcn_cvt_pk_fp8_f32(v0.x * sc, v0.y * sc, w0, false);
    w0 = __builtin_amdgcn_cvt_pk_fp8_f32(v0.z * sc, v0.w * sc, w0, true);
    w1 = __builtin_amdgcn_cvt_pk_fp8_f32(v1.x * sc, v1.y * sc, w1, false);
    w1 = __builtin_amdgcn_cvt_pk_fp8_f32(v1.z * sc, v1.w * sc, w1, true);
    int2 st = {w0, w1};
    *(int2*)(o + lane * 8) = st;
}

// ---- pos[b] = 2 * dot(emb[b],pro[c]) / (|emb[b]| |pro[c]|), pure fp32 (exact). ----
__global__ void pos_kernel(const float* __restrict__ emb, const float* __restrict__ pro,
                           const int* __restrict__ cid, float* __restrict__ rowpos) {
    int b = blockIdx.x * 4 + (threadIdx.x >> 6);
    int lane = threadIdx.x & 63;
    int c = cid[b];
    const float4* ep = (const float4*)(emb + (size_t)b * D_N + lane * 8);
    const float4* pp = (const float4*)(pro + (size_t)c * D_N + lane * 8);
    float4 e0 = ep[0], e1 = ep[1], p0 = pp[0], p1 = pp[1];
    float dp = e0.x * p0.x + e0.y * p0.y + e0.z * p0.z + e0.w * p0.w +
               e1.x * p1.x + e1.y * p1.y + e1.z * p1.z + e1.w * p1.w;
    float ee = e0.x * e0.x + e0.y * e0.y + e0.z * e0.z + e0.w * e0.w +
               e1.x * e1.x + e1.y * e1.y + e1.z * e1.z + e1.w * e1.w;
    float qq = p0.x * p0.x + p0.y * p0.y + p0.z * p0.z + p0.w * p0.w +
               p1.x * p1.x + p1.y * p1.y + p1.z * p1.z + p1.w * p1.w;
    #pragma unroll
    for (int o = 32; o; o >>= 1) {
        dp += __shfl_xor(dp, o);
        ee += __shfl_xor(ee, o);
        qq += __shfl_xor(qq, o);
    }
    if (lane == 0)
        rowpos[b] = INV_T * dp / (fmaxf(sqrtf(ee), 1e-12f) * fmaxf(sqrtf(qq), 1e-12f));
}

// ---- flash GEMM (MX-fp8, 256^2, 8-wave, counted-vmcnt pipeline):
//      rowsum[b] += sum_k exp(2*dot(emb_n[b], proto_n[k]))  ----
__global__ __launch_bounds__(512, 2) void flash_kernel(const unsigned char* __restrict__ embq,
                                                       const unsigned char* __restrict__ proq,
                                                       float* __restrict__ rowsum_g) {
    __shared__ __align__(16) unsigned char As[2][BM * BKF];  // 2 x 32 KB
    __shared__ __align__(16) unsigned char Bs[2][BN * BKF];  // 2 x 32 KB
    const int t = threadIdx.x;
    const int w = t >> 6, lane = t & 63;
    const int quad = lane >> 4, lcol = lane & 15;
    const int wm = w >> 2, wn = w & 3;               // 2M x 4N wave grid
    const int rowBase = blockIdx.x * BM;
    const int nBase = blockIdx.y * (BN * CT);

    // Fragment LDS offsets. Logical granules quad*2, quad*2+1 of the 128-B row;
    // stored position = granule ^ (row&7), row&7 == lcol&7 for all frag rows.
    const int fsw0 = (((quad << 1) | 0) ^ (lcol & 7)) << 4;
    const int fsw1 = (((quad << 1) | 1) ^ (lcol & 7)) << 4;
    const int aOff = (wm * 128 + lcol) * BKF;
    const int bOff = (wn * 64 + lcol) * BKF;

    // Staging: pass p covers LDS rows p*64 + w*8 + (lane>>3); lane's 16B lands at
    // stored granule lane&7 -> fetch global granule (lane&7)^(lane>>3).
    const int srow = w * 8 + (lane >> 3);
    const int scol = ((lane & 7) ^ (lane >> 3)) << 4;
    const unsigned char* aS = embq + (size_t)(rowBase + srow) * D_N + scol;
    const unsigned char* bS = proq + (size_t)(nBase + srow) * D_N + scol;
    const int ldsW = w * 1024;

    auto issueA = [&](int st, unsigned char* buf) {  // full A chunk: 4 loads/thread
        const unsigned char* s0 = aS + (st & 3) * BKF;
        #pragma unroll
        for (int p = 0; p < 4; p++)
            gl_lds16(s0 + (size_t)p * 64 * D_N, buf + ldsW + p * 8192);
    };
    auto issueB2 = [&](int st, unsigned char* buf, int h) {  // B half: 2 loads/thread
        const unsigned char* s0 =
            bS + (size_t)(st >> 2) * (BN * D_N) + (st & 3) * BKF + (size_t)(h * 2) * 64 * D_N;
        #pragma unroll
        for (int p = 0; p < 2; p++)
            gl_lds16(s0 + (size_t)p * 64 * D_N, buf + ldsW + (h * 2 + p) * 8192);
    };
    auto readA = [&](const unsigned char* base, int mq, intx8* af) {
        #pragma unroll
        for (int i = 0; i < 4; i++) {
            const unsigned char* rp = base + aOff + (mq * 64 + i * 16) * BKF;
            int4 lo = *(const int4*)(rp + fsw0);
            int4 hi = *(const int4*)(rp + fsw1);
            intx8 v = {lo.x, lo.y, lo.z, lo.w, hi.x, hi.y, hi.z, hi.w};
            af[i] = v;
        }
    };
    auto readB = [&](const unsigned char* base, int nq, intx8* bf) {
        #pragma unroll
        for (int j = 0; j < 2; j++) {
            const unsigned char* rp = base + bOff + (nq * 32 + j * 16) * BKF;
            int4 lo = *(const int4*)(rp + fsw0);
            int4 hi = *(const int4*)(rp + fsw1);
            intx8 v = {lo.x, lo.y, lo.z, lo.w, hi.x, hi.y, hi.z, hi.w};
            bf[j] = v;
        }
    };

    floatx4 acc[8][4];
    float rs[32];
    #pragma unroll
    for (int mt = 0; mt < 8; mt++)
        #pragma unroll
        for (int nt = 0; nt < 4; nt++) {
            floatx4 z = {0.0f, 0.0f, 0.0f, 0.0f};
            acc[mt][nt] = z;
        }
    #pragma unroll
    for (int i = 0; i < 32; i++) rs[i] = 0.0f;

    // prologue: stage step 0 fully + A(1); counted wait leaves A(1) in flight.
    issueA(0, As[0]);
    issueB2(0, Bs[0], 0);
    issueB2(0, Bs[0], 1);
    issueA(1, As[1]);
    asm volatile("s_waitcnt vmcnt(4)" ::: "memory");
    __builtin_amdgcn_s_barrier();

    #pragma unroll
    for (int s = 0; s < NT; s++) {
        unsigned char* cA = As[s & 1];
        unsigned char* cB = Bs[s & 1];
        unsigned char* nB = Bs[(s + 1) & 1];
        intx8 af[4], bf[2];

        // ---- phase (mq=0, nq=0) ----
        readA(cA, 0, af);
        readB(cB, 0, bf);
        if (s + 1 < NT) issueB2(s + 1, nB, 0);
        __builtin_amdgcn_s_barrier();
        asm volatile("s_waitcnt lgkmcnt(0)" ::: "memory");
        __builtin_amdgcn_sched_barrier(0);
        __builtin_amdgcn_s_setprio(1);
        #pragma unroll
        for (int i = 0; i < 4; i++)
            #pragma unroll
            for (int j = 0; j < 2; j++)
                acc[i][j] = __builtin_amdgcn_mfma_scale_f32_16x16x128_f8f6f4(
                    af[i], bf[j], acc[i][j], 0, 0, 0, 0x7F7F7F7F, 0, 0x7F7F7F7F);
        __builtin_amdgcn_s_setprio(0);
        __builtin_amdgcn_s_barrier();

        // ---- phase (mq=0, nq=1) ----
        readB(cB, 1, bf);
        if (s + 1 < NT) issueB2(s + 1, nB, 1);
        __builtin_amdgcn_s_barrier();
        asm volatile("s_waitcnt lgkmcnt(0)" ::: "memory");
        __builtin_amdgcn_sched_barrier(0);
        __builtin_amdgcn_s_setprio(1);
        #pragma unroll
        for (int i = 0; i < 4; i++)
            #pragma unroll
            for (int j = 0; j < 2; j++)
                acc[i][2 + j] = __builtin_amdgcn_mfma_scale_f32_16x16x128_f8f6f4(
                    af[i], bf[j], acc[i][2 + j], 0, 0, 0, 0x7F7F7F7F, 0, 0x7F7F7F7F);
        __builtin_amdgcn_s_setprio(0);
        __builtin_amdgcn_s_barrier();

        // ---- phase (mq=1, nq=0) ----
        readA(cA, 1, af);
        readB(cB, 0, bf);
        __builtin_amdgcn_s_barrier();
        asm volatile("s_waitcnt lgkmcnt(0)" ::: "memory");
        __builtin_amdgcn_sched_barrier(0);
        __builtin_amdgcn_s_setprio(1);
        #pragma unroll
        for (int i = 0; i < 4; i++)
            #pragma unroll
            for (int j = 0; j < 2; j++)
                acc[4 + i][j] = __builtin_amdgcn_mfma_scale_f32_16x16x128_f8f6f4(
                    af[i], bf[j], acc[4 + i][j], 0, 0, 0, 0x7F7F7F7F, 0, 0x7F7F7F7F);
        __builtin_amdgcn_s_setprio(0);
        __builtin_amdgcn_s_barrier();

        // ---- phase (mq=1, nq=1) ----
        readB(cB, 1, bf);
        __builtin_amdgcn_s_barrier();
        asm volatile("s_waitcnt lgkmcnt(0)" ::: "memory");
        __builtin_amdgcn_sched_barrier(0);
        __builtin_amdgcn_s_setprio(1);
        #pragma unroll
        for (int i = 0; i < 4; i++)
            #pragma unroll
            for (int j = 0; j < 2; j++)
                acc[4 + i][2 + j] = __builtin_amdgcn_mfma_scale_f32_16x16x128_f8f6f4(
                    af[i], bf[j], acc[4 + i][2 + j], 0, 0, 0, 0x7F7F7F7F, 0, 0x7F7F7F7F);
        __builtin_amdgcn_s_setprio(0);

        // ---- step boundary: issue A(s+2) into the buffer just freed, then a
        //      COUNTED wait (s+1's 8 loads done, A(s+2)'s 4 still in flight). ----
        if (s + 1 < NT) {
            if (s + 2 < NT) {
                issueA(s + 2, cA);
                asm volatile("s_waitcnt vmcnt(4)" ::: "memory");
            } else {
                asm volatile("s_waitcnt vmcnt(0)" ::: "memory");
            }
            __builtin_amdgcn_s_barrier();
        }

        // ---- per-tile epilogue (register-only; overlaps in-flight prefetch):
        //      un-scale 16*16 -> 2^-8, exp, accumulate; reset acc. ----
        if ((s & 3) == 3) {
            #pragma unroll
            for (int mt = 0; mt < 8; mt++)
                #pragma unroll
                for (int nt = 0; nt < 4; nt++)
                    #pragma unroll
                    for (int r = 0; r < 4; r++) {
                        rs[mt * 4 + r] += __expf(acc[mt][nt][r] * (INV_T / 256.0f));
                        acc[mt][nt][r] = 0.0f;
                    }
        }
    }

    // C/D layout: col=lane&15, row=quad*4+r. Reduce over the 16 columns held by
    // lcol, then one atomic per row per wave.
    #pragma unroll
    for (int i = 0; i < 32; i++) {
        #pragma unroll
        for (int o = 1; o < 16; o <<= 1) rs[i] += __shfl_xor(rs[i], o);
    }
    if (lcol == 0) {
        #pragma unroll
        for (int mt = 0; mt < 8; mt++)
            #pragma unroll
            for (int r = 0; r < 4; r++)
                atomicAdd(&rowsum_g[rowBase + wm * 128 + mt * 16 + quad * 4 + r],
                          rs[mt * 4 + r]);
    }
}

// ---- loss partial: 32 blocks, atomicAdd into out[0]; also zero cnt for EMA. ----
__global__ void loss_kernel(const float* __restrict__ rowsum, const float* __restrict__ rowpos,
                            float* __restrict__ out, int* __restrict__ cnt) {
    __shared__ float red[256];
    int t = threadIdx.x;
    int b = blockIdx.x * 256 + t;
    cnt[b * 2] = 0;
    cnt[b * 2 + 1] = 0;
    float p = rowpos[b];
    red[t] = logf(rowsum[b] - __expf(p)) - p;
    __syncthreads();
    for (int o = 128; o; o >>= 1) {
        if (t < o) red[t] += red[t + o];
        __syncthreads();
    }
    if (t == 0) atomicAdd(out, red[0] * (1.0f / (float)B_N));
}

// ---- EMA phase 1: bucket occurrence indices per cluster. ----
__global__ void ema_count(const int* __restrict__ cid, int* __restrict__ cnt,
                          int* __restrict__ bucket) {
    int b = blockIdx.x * 256 + threadIdx.x;
    int c = cid[b];
    int slot = atomicAdd(&cnt[c], 1);
    if (slot < CAP) bucket[c * CAP + slot] = b;
}

// ---- EMA phase 2: one wave per cluster, replay occurrences in ascending b. ----
__global__ void ema_apply(const float* __restrict__ emb, const float* __restrict__ pro,
                          const int* __restrict__ cnt, const int* __restrict__ bucket,
                          float* __restrict__ outp) {
    int k = blockIdx.x * 4 + (threadIdx.x >> 6);
    int lane = threadIdx.x & 63;
    int n = cnt[k];
    n = n < CAP ? n : CAP;
    const float4* pp = (const float4*)(pro + (size_t)k * D_N + lane * 8);
    float4 a0 = pp[0], a1 = pp[1];
    int myb = (lane < n) ? bucket[k * CAP + lane] : 0x7fffffff;
    for (int i = 0; i < n; i++) {
        int m = myb;
        #pragma unroll
        for (int o = 1; o < 64; o <<= 1) {
            int v = __shfl_xor(m, o);
            m = v < m ? v : m;
        }
        const float4* ep = (const float4*)(emb + (size_t)m * D_N + lane * 8);
        float4 e0 = ep[0], e1 = ep[1];
        a0.x = MOM * a0.x + (1.0f - MOM) * e0.x;
        a0.y = MOM * a0.y + (1.0f - MOM) * e0.y;
        a0.z = MOM * a0.z + (1.0f - MOM) * e0.z;
        a0.w = MOM * a0.w + (1.0f - MOM) * e0.w;
        a1.x = MOM * a1.x + (1.0f - MOM) * e1.x;
        a1.y = MOM * a1.y + (1.0f - MOM) * e1.y;
        a1.z = MOM * a1.z + (1.0f - MOM) * e1.z;
        a1.w = MOM * a1.w + (1.0f - MOM) * e1.w;
        if (myb == m) myb = 0x7fffffff;
    }
    float4* op = (float4*)(outp + (size_t)k * D_N + lane * 8);
    op[0] = a0;
    op[1] = a1;
}

extern "C" void kernel_launch(void* const* d_in, const int* in_sizes, int n_in,
                              void* d_out, int out_size, void* d_ws, size_t ws_size,
                              hipStream_t stream) {
    const float* emb = (const float*)d_in[0];
    const int* cid = (const int*)d_in[1];
    const float* pro = (const float*)d_in[2];
    float* out = (float*)d_out;

    char* ws = (char*)d_ws;
    unsigned char* embq = (unsigned char*)ws;                      // 4 MB fp8 [B,D]
    unsigned char* proq = (unsigned char*)(ws + 4194304);          // 8 MB fp8 [K,D]
    float* rowsum = (float*)(ws + 12582912);                       // [B]
    float* rowpos = (float*)(ws + 12615680);                       // [B]
    // EMA buckets alias the proq region — only touched after flash_kernel (stream
    // order): loss_kernel zeroes cnt, ema_count fills, ema_apply reads.
    int* cnt = (int*)(ws + 4194304);                               // [K]
    int* bucket = (int*)(ws + 4194304 + 65536);                    // [K, CAP]

    norm_kernel<<<(B_N + K_N) / 4, 256, 0, stream>>>(emb, pro, embq, proq, rowsum, out);
    pos_kernel<<<B_N / 4, 256, 0, stream>>>(emb, pro, cid, rowpos);
    flash_kernel<<<dim3(B_N / BM, K_N / (BN * CT)), 512, 0, stream>>>(embq, proq, rowsum);
    loss_kernel<<<B_N / 256, 256, 0, stream>>>(rowsum, rowpos, out, cnt);
    ema_count<<<B_N / 256, 256, 0, stream>>>(cid, cnt, bucket);
    ema_apply<<<K_N / 4, 256, 0, stream>>>(emb, pro, cnt, bucket, out + 1);
}

// Round 2
// 222.718 us; speedup vs baseline: 1.1299x; 1.1299x over previous
//
#include <hip/hip_runtime.h>
#include <hip/hip_bf16.h>

// PrototypeConsistentLearning: loss = mean(-pos + lse_neg), new_protos = serial EMA.
// B=8192, D=512, K=16384, T=0.5, momentum=0.9.
// R8: flash GEMM restructured to kill R7's register spill (100 MB scratch traffic,
// 140us). A panel (128x512 fp8, 64 KB) resident in LDS, loaded once per block; B
// streams as 256x128 chunks, double-buffered (2x32 KB). 8 waves (2Mx4N), per-wave
// C = 64x64 -> acc[4][4] = 64 regs + rs[16]: ~190 unified regs/wave, fits 2
// waves/SIMD with no spill. Pipeline: stage chunk+2 into the just-freed buffer,
// counted s_waitcnt vmcnt(4) on loads issued ~2 chunk-times earlier (never drains
// mid-loop), 2 barriers/chunk, s_setprio(1) around the 16-MFMA cluster. Fragments
// assembled by writing int4 halves directly into the intx8 (no v_mov tax).
// Same x16 e4m3 quantization + XOR granule swizzle (stored granule = logical ^
// (row&7); inverse applied at the global source since gl_lds writes linearly).
// pos/EMA exact fp32, unchanged.

#define B_N 8192
#define D_N 512
#define K_N 16384
#define INV_T 2.0f
#define MOM 0.9f

#define BM 128          // A rows per block (resident panel)
#define BKF 128         // K bytes per chunk
#define BTR 256         // B rows per tile
#define KSPLIT 4        // grid.y; each block covers K_N/KSPLIT = 4096 B-rows
#define NCH 64          // chunk-steps per block: (4096/BTR=16 tiles) * (D_N/BKF=4)
#define CAP 64

typedef __attribute__((ext_vector_type(8))) int intx8;
typedef __attribute__((ext_vector_type(4))) float floatx4;

__device__ __forceinline__ void gl_lds16(const void* g, void* lds) {
    __builtin_amdgcn_global_load_lds(
        (const __attribute__((address_space(1))) void*)g,
        (__attribute__((address_space(3))) void*)lds, 16, 0, 0);
}

__device__ __forceinline__ intx8 frag2(const unsigned char* rp, int o0, int o1) {
    intx8 v;
    ((int4*)&v)[0] = *(const int4*)(rp + o0);
    ((int4*)&v)[1] = *(const int4*)(rp + o1);
    return v;
}

// ---- normalize rows (fp32) -> e4m3 fp8 scaled by 16; also zero rowsum/out[0]. ----
__global__ void norm_kernel(const float* __restrict__ emb, const float* __restrict__ pro,
                            unsigned char* __restrict__ embq, unsigned char* __restrict__ proq,
                            float* __restrict__ rowsum, float* __restrict__ out) {
    if (blockIdx.x < 32) rowsum[blockIdx.x * 256 + threadIdx.x] = 0.0f;
    if (blockIdx.x == 32 && threadIdx.x == 0) out[0] = 0.0f;
    int row = blockIdx.x * 4 + (threadIdx.x >> 6);
    int lane = threadIdx.x & 63;
    const float* x;
    unsigned char* o;
    if (row < B_N) {
        x = emb + (size_t)row * D_N;
        o = embq + (size_t)row * D_N;
    } else {
        x = pro + (size_t)(row - B_N) * D_N;
        o = proq + (size_t)(row - B_N) * D_N;
    }
    const float4* xp = (const float4*)(x + lane * 8);
    float4 v0 = xp[0];
    float4 v1 = xp[1];
    float ss = v0.x * v0.x + v0.y * v0.y + v0.z * v0.z + v0.w * v0.w +
               v1.x * v1.x + v1.y * v1.y + v1.z * v1.z + v1.w * v1.w;
    #pragma unroll
    for (int of = 32; of; of >>= 1) ss += __shfl_xor(ss, of);
    float sc = 16.0f / fmaxf(sqrtf(ss), 1e-12f);  // x16: e4m3 keeps full mantissa range
    int w0 = 0, w1 = 0;
    w0 = __builtin_amdgcn_cvt_pk_fp8_f32(v0.x * sc, v0.y * sc, w0, false);
    w0 = __builtin_amdgcn_cvt_pk_fp8_f32(v0.z * sc, v0.w * sc, w0, true);
    w1 = __builtin_amdgcn_cvt_pk_fp8_f32(v1.x * sc, v1.y * sc, w1, false);
    w1 = __builtin_amdgcn_cvt_pk_fp8_f32(v1.z * sc, v1.w * sc, w1, true);
    int2 st = {w0, w1};
    *(int2*)(o + lane * 8) = st;
}

// ---- pos[b] = 2 * dot(emb[b],pro[c]) / (|emb[b]| |pro[c]|), pure fp32 (exact). ----
__global__ void pos_kernel(const float* __restrict__ emb, const float* __restrict__ pro,
                           const int* __restrict__ cid, float* __restrict__ rowpos) {
    int b = blockIdx.x * 4 + (threadIdx.x >> 6);
    int lane = threadIdx.x & 63;
    int c = cid[b];
    const float4* ep = (const float4*)(emb + (size_t)b * D_N + lane * 8);
    const float4* pp = (const float4*)(pro + (size_t)c * D_N + lane * 8);
    float4 e0 = ep[0], e1 = ep[1], p0 = pp[0], p1 = pp[1];
    float dp = e0.x * p0.x + e0.y * p0.y + e0.z * p0.z + e0.w * p0.w +
               e1.x * p1.x + e1.y * p1.y + e1.z * p1.z + e1.w * p1.w;
    float ee = e0.x * e0.x + e0.y * e0.y + e0.z * e0.z + e0.w * e0.w +
               e1.x * e1.x + e1.y * e1.y + e1.z * e1.z + e1.w * e1.w;
    float qq = p0.x * p0.x + p0.y * p0.y + p0.z * p0.z + p0.w * p0.w +
               p1.x * p1.x + p1.y * p1.y + p1.z * p1.z + p1.w * p1.w;
    #pragma unroll
    for (int o = 32; o; o >>= 1) {
        dp += __shfl_xor(dp, o);
        ee += __shfl_xor(ee, o);
        qq += __shfl_xor(qq, o);
    }
    if (lane == 0)
        rowpos[b] = INV_T * dp / (fmaxf(sqrtf(ee), 1e-12f) * fmaxf(sqrtf(qq), 1e-12f));
}

// ---- flash GEMM (MX-fp8, A-resident-LDS, counted-vmcnt stream over B):
//      rowsum[b] += sum_k exp(2*dot(emb_n[b], proto_n[k]))  ----
__global__ __launch_bounds__(512, 2) void flash_kernel(const unsigned char* __restrict__ embq,
                                                       const unsigned char* __restrict__ proq,
                                                       float* __restrict__ rowsum_g) {
    __shared__ __align__(16) unsigned char As[BM * D_N];      // 64 KB, resident
    __shared__ __align__(16) unsigned char Bs[2][BTR * BKF];  // 2 x 32 KB, dbuf
    const int t = threadIdx.x;
    const int w = t >> 6, lane = t & 63;
    const int quad = lane >> 4, lcol = lane & 15;
    const int wm = w >> 2, wn = w & 3;  // 2M x 4N wave grid; per-wave C = 64x64
    const int rowBase = blockIdx.x * BM;
    const int kb = blockIdx.y * (K_N / KSPLIT);

    // Fragment granule offsets: logical granules quad*2, quad*2+1 of a 128-B
    // chunk-row; stored position = granule ^ (row&7); frag rows have row&7==lcol&7.
    const int fsw0 = (((quad << 1) | 0) ^ (lcol & 7)) << 4;
    const int fsw1 = (((quad << 1) | 1) ^ (lcol & 7)) << 4;
    const unsigned char* aF = As + (size_t)(wm * 64 + lcol) * D_N;
    const int ldsW = w * 1024;

    // A staging: pass p writes LDS bytes p*8192 + t*16 -> row p*16 + w*2 + (lane>>5),
    // chunk (lane>>3)&3, stored granule lane&7 -> source granule (lane&7)^(row&7).
    const int aRow = w * 2 + (lane >> 5);
    const unsigned char* aS = embq + (size_t)(rowBase + aRow) * D_N +
                              (((lane >> 3) & 3) << 7) + (((lane & 7) ^ (aRow & 7)) << 4);
    // B staging: pass p writes rows p*64 + w*8 + (lane>>3) of the 128-B chunk rows;
    // stored granule lane&7 -> source granule (lane&7)^((lane>>3)&7).
    const unsigned char* bS = proq + (size_t)(kb + w * 8 + (lane >> 3)) * D_N +
                              (((lane & 7) ^ ((lane >> 3) & 7)) << 4);

    floatx4 acc[4][4];
    float rs[16];
    #pragma unroll
    for (int i = 0; i < 4; i++)
        #pragma unroll
        for (int j = 0; j < 4; j++) {
            floatx4 z = {0.0f, 0.0f, 0.0f, 0.0f};
            acc[i][j] = z;
        }
    #pragma unroll
    for (int i = 0; i < 16; i++) rs[i] = 0.0f;

    // ---- prologue: A panel (8 passes) + B chunk0 -> Bs[0], chunk1 -> Bs[1]. ----
    #pragma unroll
    for (int p = 0; p < 8; p++)
        gl_lds16(aS + p * 8192, As + p * 8192 + ldsW);
    #pragma unroll
    for (int p = 0; p < 4; p++)
        gl_lds16(bS + (size_t)p * 64 * D_N, Bs[0] + p * 8192 + ldsW);
    #pragma unroll
    for (int p = 0; p < 4; p++)
        gl_lds16(bS + (size_t)p * 64 * D_N + BKF, Bs[1] + p * 8192 + ldsW);
    // outstanding: A 8 + B0 4 + B1 4 = 16; wait until only B1's 4 remain.
    asm volatile("s_waitcnt vmcnt(4)" ::: "memory");
    __builtin_amdgcn_s_barrier();

    for (int cc = 0; cc < NCH; cc++) {
        const unsigned char* bufc = Bs[cc & 1];
        const unsigned char* ra = aF + ((cc & 3) << 7);
        const unsigned char* rb = bufc + (size_t)(wn * 64 + lcol) * BKF;

        intx8 af[4], bf[4];
        #pragma unroll
        for (int i = 0; i < 4; i++)
            af[i] = frag2(ra + i * (16 * D_N), fsw0, fsw1);
        #pragma unroll
        for (int j = 0; j < 4; j++)
            bf[j] = frag2(rb + j * (16 * BKF), fsw0, fsw1);

        __builtin_amdgcn_s_setprio(1);
        #pragma unroll
        for (int i = 0; i < 4; i++)
            #pragma unroll
            for (int j = 0; j < 4; j++)
                acc[i][j] = __builtin_amdgcn_mfma_scale_f32_16x16x128_f8f6f4(
                    af[i], bf[j], acc[i][j], 0, 0, 0, 0x7F7F7F7F, 0, 0x7F7F7F7F);
        __builtin_amdgcn_s_setprio(0);

        // tile epilogue every 4 chunks (K complete): exp + accumulate, reset acc.
        // VALU-only; overlaps other waves' MFMA (separate pipes).
        if ((cc & 3) == 3) {
            #pragma unroll
            for (int i = 0; i < 4; i++)
                #pragma unroll
                for (int j = 0; j < 4; j++)
                    #pragma unroll
                    for (int r = 0; r < 4; r++) {
                        rs[i * 4 + r] += __expf(acc[i][j][r] * (INV_T / 256.0f));
                        acc[i][j][r] = 0.0f;
                    }
        }

        // all waves done reading Bs[cc&1] (MFMA operand deps forced lgkm waits).
        asm volatile("s_barrier" ::: "memory");
        if (cc + 2 < NCH) {
            // stage chunk cc+2 into the buffer just freed.
            const unsigned char* s =
                bS + (size_t)(((cc + 2) >> 2) * BTR) * D_N + (((cc + 2) & 3) << 7);
            unsigned char* d = (unsigned char*)Bs[cc & 1] + ldsW;
            #pragma unroll
            for (int p = 0; p < 4; p++)
                gl_lds16(s + (size_t)p * 64 * D_N, d + p * 8192);
            // chunk cc+1's 4 loads (issued ~2 chunk-times ago) retired; cc+2 in flight.
            asm volatile("s_waitcnt vmcnt(4)" ::: "memory");
        } else {
            asm volatile("s_waitcnt vmcnt(0)" ::: "memory");
        }
        asm volatile("s_barrier" ::: "memory");
    }

    // C/D layout: col=lane&15, row=quad*4+r. rs[i*4+r] holds the partial sum for
    // row wm*64+i*16+quad*4+r over this wave's 64 columns x this lcol; reduce
    // over the 16 lcol lanes (stays within the quad), then one atomic per row.
    #pragma unroll
    for (int i = 0; i < 16; i++) {
        #pragma unroll
        for (int o = 1; o < 16; o <<= 1) rs[i] += __shfl_xor(rs[i], o);
    }
    if (lcol == 0) {
        #pragma unroll
        for (int i = 0; i < 4; i++)
            #pragma unroll
            for (int r = 0; r < 4; r++)
                atomicAdd(&rowsum_g[rowBase + wm * 64 + i * 16 + quad * 4 + r],
                          rs[i * 4 + r]);
    }
}

// ---- loss partial: 32 blocks, atomicAdd into out[0]; also zero cnt for EMA. ----
__global__ void loss_kernel(const float* __restrict__ rowsum, const float* __restrict__ rowpos,
                            float* __restrict__ out, int* __restrict__ cnt) {
    __shared__ float red[256];
    int t = threadIdx.x;
    int b = blockIdx.x * 256 + t;
    cnt[b * 2] = 0;
    cnt[b * 2 + 1] = 0;
    float p = rowpos[b];
    red[t] = logf(rowsum[b] - __expf(p)) - p;
    __syncthreads();
    for (int o = 128; o; o >>= 1) {
        if (t < o) red[t] += red[t + o];
        __syncthreads();
    }
    if (t == 0) atomicAdd(out, red[0] * (1.0f / (float)B_N));
}

// ---- EMA phase 1: bucket occurrence indices per cluster. ----
__global__ void ema_count(const int* __restrict__ cid, int* __restrict__ cnt,
                          int* __restrict__ bucket) {
    int b = blockIdx.x * 256 + threadIdx.x;
    int c = cid[b];
    int slot = atomicAdd(&cnt[c], 1);
    if (slot < CAP) bucket[c * CAP + slot] = b;
}

// ---- EMA phase 2: one wave per cluster, replay occurrences in ascending b. ----
__global__ void ema_apply(const float* __restrict__ emb, const float* __restrict__ pro,
                          const int* __restrict__ cnt, const int* __restrict__ bucket,
                          float* __restrict__ outp) {
    int k = blockIdx.x * 4 + (threadIdx.x >> 6);
    int lane = threadIdx.x & 63;
    int n = cnt[k];
    n = n < CAP ? n : CAP;
    const float4* pp = (const float4*)(pro + (size_t)k * D_N + lane * 8);
    float4 a0 = pp[0], a1 = pp[1];
    int myb = (lane < n) ? bucket[k * CAP + lane] : 0x7fffffff;
    for (int i = 0; i < n; i++) {
        int m = myb;
        #pragma unroll
        for (int o = 1; o < 64; o <<= 1) {
            int v = __shfl_xor(m, o);
            m = v < m ? v : m;
        }
        const float4* ep = (const float4*)(emb + (size_t)m * D_N + lane * 8);
        float4 e0 = ep[0], e1 = ep[1];
        a0.x = MOM * a0.x + (1.0f - MOM) * e0.x;
        a0.y = MOM * a0.y + (1.0f - MOM) * e0.y;
        a0.z = MOM * a0.z + (1.0f - MOM) * e0.z;
        a0.w = MOM * a0.w + (1.0f - MOM) * e0.w;
        a1.x = MOM * a1.x + (1.0f - MOM) * e1.x;
        a1.y = MOM * a1.y + (1.0f - MOM) * e1.y;
        a1.z = MOM * a1.z + (1.0f - MOM) * e1.z;
        a1.w = MOM * a1.w + (1.0f - MOM) * e1.w;
        if (myb == m) myb = 0x7fffffff;
    }
    float4* op = (float4*)(outp + (size_t)k * D_N + lane * 8);
    op[0] = a0;
    op[1] = a1;
}

extern "C" void kernel_launch(void* const* d_in, const int* in_sizes, int n_in,
                              void* d_out, int out_size, void* d_ws, size_t ws_size,
                              hipStream_t stream) {
    const float* emb = (const float*)d_in[0];
    const int* cid = (const int*)d_in[1];
    const float* pro = (const float*)d_in[2];
    float* out = (float*)d_out;

    char* ws = (char*)d_ws;
    unsigned char* embq = (unsigned char*)ws;                      // 4 MB fp8 [B,D]
    unsigned char* proq = (unsigned char*)(ws + 4194304);          // 8 MB fp8 [K,D]
    float* rowsum = (float*)(ws + 12582912);                       // [B]
    float* rowpos = (float*)(ws + 12615680);                       // [B]
    // EMA buckets alias the proq region — only touched after flash_kernel (stream
    // order): loss_kernel zeroes cnt, ema_count fills, ema_apply reads.
    int* cnt = (int*)(ws + 4194304);                               // [K]
    int* bucket = (int*)(ws + 4194304 + 65536);                    // [K, CAP]

    norm_kernel<<<(B_N + K_N) / 4, 256, 0, stream>>>(emb, pro, embq, proq, rowsum, out);
    pos_kernel<<<B_N / 4, 256, 0, stream>>>(emb, pro, cid, rowpos);
    flash_kernel<<<dim3(B_N / BM, KSPLIT), 512, 0, stream>>>(embq, proq, rowsum);
    loss_kernel<<<B_N / 256, 256, 0, stream>>>(rowsum, rowpos, out, cnt);
    ema_count<<<B_N / 256, 256, 0, stream>>>(cid, cnt, bucket);
    ema_apply<<<K_N / 4, 256, 0, stream>>>(emb, pro, cnt, bucket, out + 1);
}

// Round 5
// 200.342 us; speedup vs baseline: 1.2561x; 1.1117x over previous
//
#include <hip/hip_runtime.h>
#include <hip/hip_bf16.h>

// PrototypeConsistentLearning: loss = mean(-pos + lse_neg), new_protos = serial EMA.
// B=8192, D=512, K=16384, T=0.5, momentum=0.9.
// R11 == R9 semantics with de-risked codegen (R9/R10 benches died in-container
// twice with no counters; R8 ran fine on the same harness). Changes vs R9:
// named af0/af1 ping-pong arrays via a fully-static 4-phase macro (no array
// indexing that could ever go dynamic -> scratch), and uniform
// __builtin_amdgcn_s_barrier() for all barriers. Schedule identical:
// A panel (128x512 fp8, 64 KB) resident in LDS; B streams 256x128 chunks,
// double-buffered (2x32 KB). A fragments register-prefetched one chunk-step
// ahead (legal: A loop-invariant + resident), so post-barrier critical-path LDS
// is only bf[4] (32 KB/block-step ~256 cy << 1106 cy MFMA). Counted-vmcnt B
// pipeline: stage chunk cc+2 into the just-freed buffer, s_waitcnt vmcnt(4)
// (never drains mid-loop), 2 barriers/step, setprio(1) around the 16-MFMA
// cluster. ~190 live regs (acc 64 + af 64 + bf 32 + rs 16) -- no spill.
// Same x16 e4m3 quantization + XOR granule swizzle (stored granule = logical ^
// (row&7); inverse applied at the global source since gl_lds writes linearly).
// pos/EMA exact fp32, unchanged.

#define B_N 8192
#define D_N 512
#define K_N 16384
#define INV_T 2.0f
#define MOM 0.9f

#define BM 128          // A rows per block (resident panel)
#define BKF 128         // K bytes per chunk
#define BTR 256         // B rows per tile
#define KSPLIT 4        // grid.y; each block covers K_N/KSPLIT = 4096 B-rows
#define NTILE 16        // B tiles per block (4096 / BTR)
#define CAP 64

typedef __attribute__((ext_vector_type(8))) int intx8;
typedef __attribute__((ext_vector_type(4))) float floatx4;

__device__ __forceinline__ void gl_lds16(const void* g, void* lds) {
    __builtin_amdgcn_global_load_lds(
        (const __attribute__((address_space(1))) void*)g,
        (__attribute__((address_space(3))) void*)lds, 16, 0, 0);
}

__device__ __forceinline__ intx8 frag2(const unsigned char* rp, int o0, int o1) {
    intx8 v;
    ((int4*)&v)[0] = *(const int4*)(rp + o0);
    ((int4*)&v)[1] = *(const int4*)(rp + o1);
    return v;
}

// ---- normalize rows (fp32) -> e4m3 fp8 scaled by 16; also zero rowsum/out[0]. ----
__global__ void norm_kernel(const float* __restrict__ emb, const float* __restrict__ pro,
                            unsigned char* __restrict__ embq, unsigned char* __restrict__ proq,
                            float* __restrict__ rowsum, float* __restrict__ out) {
    if (blockIdx.x < 32) rowsum[blockIdx.x * 256 + threadIdx.x] = 0.0f;
    if (blockIdx.x == 32 && threadIdx.x == 0) out[0] = 0.0f;
    int row = blockIdx.x * 4 + (threadIdx.x >> 6);
    int lane = threadIdx.x & 63;
    const float* x;
    unsigned char* o;
    if (row < B_N) {
        x = emb + (size_t)row * D_N;
        o = embq + (size_t)row * D_N;
    } else {
        x = pro + (size_t)(row - B_N) * D_N;
        o = proq + (size_t)(row - B_N) * D_N;
    }
    const float4* xp = (const float4*)(x + lane * 8);
    float4 v0 = xp[0];
    float4 v1 = xp[1];
    float ss = v0.x * v0.x + v0.y * v0.y + v0.z * v0.z + v0.w * v0.w +
               v1.x * v1.x + v1.y * v1.y + v1.z * v1.z + v1.w * v1.w;
    #pragma unroll
    for (int of = 32; of; of >>= 1) ss += __shfl_xor(ss, of);
    float sc = 16.0f / fmaxf(sqrtf(ss), 1e-12f);  // x16: e4m3 keeps full mantissa range
    int w0 = 0, w1 = 0;
    w0 = __builtin_amdgcn_cvt_pk_fp8_f32(v0.x * sc, v0.y * sc, w0, false);
    w0 = __builtin_amdgcn_cvt_pk_fp8_f32(v0.z * sc, v0.w * sc, w0, true);
    w1 = __builtin_amdgcn_cvt_pk_fp8_f32(v1.x * sc, v1.y * sc, w1, false);
    w1 = __builtin_amdgcn_cvt_pk_fp8_f32(v1.z * sc, v1.w * sc, w1, true);
    int2 st = {w0, w1};
    *(int2*)(o + lane * 8) = st;
}

// ---- pos[b] = 2 * dot(emb[b],pro[c]) / (|emb[b]| |pro[c]|), pure fp32 (exact). ----
__global__ void pos_kernel(const float* __restrict__ emb, const float* __restrict__ pro,
                           const int* __restrict__ cid, float* __restrict__ rowpos) {
    int b = blockIdx.x * 4 + (threadIdx.x >> 6);
    int lane = threadIdx.x & 63;
    int c = cid[b];
    const float4* ep = (const float4*)(emb + (size_t)b * D_N + lane * 8);
    const float4* pp = (const float4*)(pro + (size_t)c * D_N + lane * 8);
    float4 e0 = ep[0], e1 = ep[1], p0 = pp[0], p1 = pp[1];
    float dp = e0.x * p0.x + e0.y * p0.y + e0.z * p0.z + e0.w * p0.w +
               e1.x * p1.x + e1.y * p1.y + e1.z * p1.z + e1.w * p1.w;
    float ee = e0.x * e0.x + e0.y * e0.y + e0.z * e0.z + e0.w * e0.w +
               e1.x * e1.x + e1.y * e1.y + e1.z * e1.z + e1.w * e1.w;
    float qq = p0.x * p0.x + p0.y * p0.y + p0.z * p0.z + p0.w * p0.w +
               p1.x * p1.x + p1.y * p1.y + p1.z * p1.z + p1.w * p1.w;
    #pragma unroll
    for (int o = 32; o; o >>= 1) {
        dp += __shfl_xor(dp, o);
        ee += __shfl_xor(ee, o);
        qq += __shfl_xor(qq, o);
    }
    if (lane == 0)
        rowpos[b] = INV_T * dp / (fmaxf(sqrtf(ee), 1e-12f) * fmaxf(sqrtf(qq), 1e-12f));
}

// One chunk-step of the flash K-loop. CH in 0..3 (compile-time literal); AFC =
// current A-frag regs, AFN = next (prefetched under this step's MFMA window).
#define FLASH_STEP(CH, AFC, AFN)                                                      \
    do {                                                                              \
        const unsigned char* rb = Bs[(CH) & 1] + (size_t)(wn * 64 + lcol) * BKF;      \
        intx8 bf[4];                                                                  \
        _Pragma("unroll")                                                             \
        for (int j = 0; j < 4; j++)                                                   \
            bf[j] = frag2(rb + j * (16 * BKF), fsw0, fsw1);                           \
        if (tt < NTILE - 1 || (CH) < 3) {                                             \
            const unsigned char* ran = aF + ((((CH) + 1) & 3) << 7);                  \
            _Pragma("unroll")                                                         \
            for (int i = 0; i < 4; i++)                                               \
                AFN[i] = frag2(ran + i * (16 * D_N), fsw0, fsw1);                     \
        }                                                                             \
        __builtin_amdgcn_s_setprio(1);                                                \
        _Pragma("unroll")                                                             \
        for (int i = 0; i < 4; i++)                                                   \
            _Pragma("unroll")                                                         \
            for (int j = 0; j < 4; j++)                                               \
                acc[i][j] = __builtin_amdgcn_mfma_scale_f32_16x16x128_f8f6f4(         \
                    AFC[i], bf[j], acc[i][j], 0, 0, 0, 0x7F7F7F7F, 0, 0x7F7F7F7F);    \
        __builtin_amdgcn_s_setprio(0);                                                \
        if ((CH) == 3) {                                                              \
            _Pragma("unroll")                                                         \
            for (int i = 0; i < 4; i++)                                               \
                _Pragma("unroll")                                                     \
                for (int j = 0; j < 4; j++)                                           \
                    _Pragma("unroll")                                                 \
                    for (int r = 0; r < 4; r++) {                                     \
                        rs[i * 4 + r] += __expf(acc[i][j][r] * (INV_T / 256.0f));     \
                        acc[i][j][r] = 0.0f;                                          \
                    }                                                                 \
        }                                                                             \
        __builtin_amdgcn_s_barrier();                                                 \
        if (tt < NTILE - 1 || (CH) < 2) {                                             \
            const unsigned char* s =                                                  \
                bT + (((CH) >= 2) ? (size_t)BTR * D_N : 0) + ((((CH) + 2) & 3) << 7); \
            unsigned char* d = (unsigned char*)Bs[(CH) & 1] + ldsW;                   \
            _Pragma("unroll")                                                         \
            for (int p = 0; p < 4; p++)                                               \
                gl_lds16(s + (size_t)p * 64 * D_N, d + p * 8192);                     \
            asm volatile("s_waitcnt vmcnt(4)" ::: "memory");                          \
        } else {                                                                      \
            asm volatile("s_waitcnt vmcnt(0)" ::: "memory");                          \
        }                                                                             \
        __builtin_amdgcn_s_barrier();                                                 \
    } while (0)

// ---- flash GEMM (MX-fp8, A-resident-LDS + reg-prefetched A frags):
//      rowsum[b] += sum_k exp(2*dot(emb_n[b], proto_n[k]))  ----
__global__ __launch_bounds__(512, 2) void flash_kernel(const unsigned char* __restrict__ embq,
                                                       const unsigned char* __restrict__ proq,
                                                       float* __restrict__ rowsum_g) {
    __shared__ __align__(16) unsigned char As[BM * D_N];      // 64 KB, resident
    __shared__ __align__(16) unsigned char Bs[2][BTR * BKF];  // 2 x 32 KB, dbuf
    const int t = threadIdx.x;
    const int w = t >> 6, lane = t & 63;
    const int quad = lane >> 4, lcol = lane & 15;
    const int wm = w >> 2, wn = w & 3;  // 2M x 4N wave grid; per-wave C = 64x64
    const int rowBase = blockIdx.x * BM;
    const int kb = blockIdx.y * (K_N / KSPLIT);

    // Fragment granule offsets: logical granules quad*2, quad*2+1 of a 128-B
    // chunk-row; stored position = granule ^ (row&7); frag rows have row&7==lcol&7.
    const int fsw0 = (((quad << 1) | 0) ^ (lcol & 7)) << 4;
    const int fsw1 = (((quad << 1) | 1) ^ (lcol & 7)) << 4;
    const unsigned char* aF = As + (size_t)(wm * 64 + lcol) * D_N;
    const int ldsW = w * 1024;

    // A staging: pass p writes LDS bytes p*8192 + t*16 -> row p*16 + w*2 + (lane>>5),
    // chunk (lane>>3)&3, stored granule lane&7 -> source granule (lane&7)^(row&7).
    const int aRow = w * 2 + (lane >> 5);
    const unsigned char* aS = embq + (size_t)(rowBase + aRow) * D_N +
                              (((lane >> 3) & 3) << 7) + (((lane & 7) ^ (aRow & 7)) << 4);
    // B staging: pass p writes rows p*64 + w*8 + (lane>>3) of the 128-B chunk rows;
    // stored granule lane&7 -> source granule (lane&7)^((lane>>3)&7).
    const unsigned char* bS = proq + (size_t)(kb + w * 8 + (lane >> 3)) * D_N +
                              (((lane & 7) ^ ((lane >> 3) & 7)) << 4);

    floatx4 acc[4][4];
    float rs[16];
    #pragma unroll
    for (int i = 0; i < 4; i++)
        #pragma unroll
        for (int j = 0; j < 4; j++) {
            floatx4 z = {0.0f, 0.0f, 0.0f, 0.0f};
            acc[i][j] = z;
        }
    #pragma unroll
    for (int i = 0; i < 16; i++) rs[i] = 0.0f;

    // ---- prologue: A panel (8 passes) + B chunk0 -> Bs[0], chunk1 -> Bs[1]. ----
    #pragma unroll
    for (int p = 0; p < 8; p++)
        gl_lds16(aS + p * 8192, As + p * 8192 + ldsW);
    #pragma unroll
    for (int p = 0; p < 4; p++)
        gl_lds16(bS + (size_t)p * 64 * D_N, Bs[0] + p * 8192 + ldsW);
    #pragma unroll
    for (int p = 0; p < 4; p++)
        gl_lds16(bS + (size_t)p * 64 * D_N + BKF, Bs[1] + p * 8192 + ldsW);
    // outstanding 16; wait until only B1's 4 remain -> A + B0 complete.
    asm volatile("s_waitcnt vmcnt(4)" ::: "memory");
    __builtin_amdgcn_s_barrier();

    // A fragments for chunk 0 -> af0 (named ping-pong reg double-buffer).
    intx8 af0[4], af1[4];
    #pragma unroll
    for (int i = 0; i < 4; i++)
        af0[i] = frag2(aF + i * (16 * D_N), fsw0, fsw1);

    const unsigned char* bT = bS;  // per-tile staging source base
    for (int tt = 0; tt < NTILE; tt++) {
        FLASH_STEP(0, af0, af1);
        FLASH_STEP(1, af1, af0);
        FLASH_STEP(2, af0, af1);
        FLASH_STEP(3, af1, af0);
        bT += (size_t)BTR * D_N;
    }

    // C/D layout: col=lane&15, row=quad*4+r. rs[i*4+r] holds the partial sum for
    // row wm*64+i*16+quad*4+r over this wave's 64 columns x this lcol; reduce
    // over the 16 lcol lanes (stays within the quad), then one atomic per row.
    #pragma unroll
    for (int i = 0; i < 16; i++) {
        #pragma unroll
        for (int o = 1; o < 16; o <<= 1) rs[i] += __shfl_xor(rs[i], o);
    }
    if (lcol == 0) {
        #pragma unroll
        for (int i = 0; i < 4; i++)
            #pragma unroll
            for (int r = 0; r < 4; r++)
                atomicAdd(&rowsum_g[rowBase + wm * 64 + i * 16 + quad * 4 + r],
                          rs[i * 4 + r]);
    }
}

// ---- loss partial: 32 blocks, atomicAdd into out[0]; also zero cnt for EMA. ----
__global__ void loss_kernel(const float* __restrict__ rowsum, const float* __restrict__ rowpos,
                            float* __restrict__ out, int* __restrict__ cnt) {
    __shared__ float red[256];
    int t = threadIdx.x;
    int b = blockIdx.x * 256 + t;
    cnt[b * 2] = 0;
    cnt[b * 2 + 1] = 0;
    float p = rowpos[b];
    red[t] = logf(rowsum[b] - __expf(p)) - p;
    __syncthreads();
    for (int o = 128; o; o >>= 1) {
        if (t < o) red[t] += red[t + o];
        __syncthreads();
    }
    if (t == 0) atomicAdd(out, red[0] * (1.0f / (float)B_N));
}

// ---- EMA phase 1: bucket occurrence indices per cluster. ----
__global__ void ema_count(const int* __restrict__ cid, int* __restrict__ cnt,
                          int* __restrict__ bucket) {
    int b = blockIdx.x * 256 + threadIdx.x;
    int c = cid[b];
    int slot = atomicAdd(&cnt[c], 1);
    if (slot < CAP) bucket[c * CAP + slot] = b;
}

// ---- EMA phase 2: one wave per cluster, replay occurrences in ascending b. ----
__global__ void ema_apply(const float* __restrict__ emb, const float* __restrict__ pro,
                          const int* __restrict__ cnt, const int* __restrict__ bucket,
                          float* __restrict__ outp) {
    int k = blockIdx.x * 4 + (threadIdx.x >> 6);
    int lane = threadIdx.x & 63;
    int n = cnt[k];
    n = n < CAP ? n : CAP;
    const float4* pp = (const float4*)(pro + (size_t)k * D_N + lane * 8);
    float4 a0 = pp[0], a1 = pp[1];
    int myb = (lane < n) ? bucket[k * CAP + lane] : 0x7fffffff;
    for (int i = 0; i < n; i++) {
        int m = myb;
        #pragma unroll
        for (int o = 1; o < 64; o <<= 1) {
            int v = __shfl_xor(m, o);
            m = v < m ? v : m;
        }
        const float4* ep = (const float4*)(emb + (size_t)m * D_N + lane * 8);
        float4 e0 = ep[0], e1 = ep[1];
        a0.x = MOM * a0.x + (1.0f - MOM) * e0.x;
        a0.y = MOM * a0.y + (1.0f - MOM) * e0.y;
        a0.z = MOM * a0.z + (1.0f - MOM) * e0.z;
        a0.w = MOM * a0.w + (1.0f - MOM) * e0.w;
        a1.x = MOM * a1.x + (1.0f - MOM) * e1.x;
        a1.y = MOM * a1.y + (1.0f - MOM) * e1.y;
        a1.z = MOM * a1.z + (1.0f - MOM) * e1.z;
        a1.w = MOM * a1.w + (1.0f - MOM) * e1.w;
        if (myb == m) myb = 0x7fffffff;
    }
    float4* op = (float4*)(outp + (size_t)k * D_N + lane * 8);
    op[0] = a0;
    op[1] = a1;
}

extern "C" void kernel_launch(void* const* d_in, const int* in_sizes, int n_in,
                              void* d_out, int out_size, void* d_ws, size_t ws_size,
                              hipStream_t stream) {
    const float* emb = (const float*)d_in[0];
    const int* cid = (const int*)d_in[1];
    const float* pro = (const float*)d_in[2];
    float* out = (float*)d_out;

    char* ws = (char*)d_ws;
    unsigned char* embq = (unsigned char*)ws;                      // 4 MB fp8 [B,D]
    unsigned char* proq = (unsigned char*)(ws + 4194304);          // 8 MB fp8 [K,D]
    float* rowsum = (float*)(ws + 12582912);                       // [B]
    float* rowpos = (float*)(ws + 12615680);                       // [B]
    // EMA buckets alias the proq region — only touched after flash_kernel (stream
    // order): loss_kernel zeroes cnt, ema_count fills, ema_apply reads.
    int* cnt = (int*)(ws + 4194304);                               // [K]
    int* bucket = (int*)(ws + 4194304 + 65536);                    // [K, CAP]

    norm_kernel<<<(B_N + K_N) / 4, 256, 0, stream>>>(emb, pro, embq, proq, rowsum, out);
    pos_kernel<<<B_N / 4, 256, 0, stream>>>(emb, pro, cid, rowpos);
    flash_kernel<<<dim3(B_N / BM, KSPLIT), 512, 0, stream>>>(embq, proq, rowsum);
    loss_kernel<<<B_N / 256, 256, 0, stream>>>(rowsum, rowpos, out, cnt);
    ema_count<<<B_N / 256, 256, 0, stream>>>(cid, cnt, bucket);
    ema_apply<<<K_N / 4, 256, 0, stream>>>(emb, pro, cnt, bucket, out + 1);
}